// Round 8
// baseline (20570.746 us; speedup 1.0000x reference)
//
#include <hip/hip_runtime.h>
#include <cstdint>
#include <cstddef>

#define B_   2
#define N_   8192
#define M_   2048
#define K_   32
#define C0_  64
#define C1_  128
#define C2_  256
#define CIN_ 67

// Exact-match distance: reference computes sum((a-b)**2, axis=-1) in f32 as
// ((dx^2 + dy^2) + dz^2) with no FMA contraction. _rn intrinsics forbid
// contract-fast fma fusion (would flip argmax / radius-boundary decisions).
__device__ __forceinline__ float sqdist_rn(float ax, float ay, float az,
                                           float bx, float by, float bz) {
  float dx = __fsub_rn(ax, bx);
  float dy = __fsub_rn(ay, by);
  float dz = __fsub_rn(az, bz);
  return __fadd_rn(__fadd_rn(__fmul_rn(dx, dx), __fmul_rn(dy, dy)),
                   __fmul_rn(dz, dz));
}

__device__ __forceinline__ int morton8(int ix, int iy, int iz) {
  int m = 0;
#pragma unroll
  for (int b = 0; b < 3; ++b) {
    m |= (((ix >> b) & 1) << (3 * b + 2)) | (((iy >> b) & 1) << (3 * b + 1)) |
         (((iz >> b) & 1) << (3 * b + 0));
  }
  return m;
}

// u64 max across the wave via paired DPP (row_shr 1/2/4/8, row_bcast 15/31);
// cumulative max lands in lane 63. Exact tie-break baked into the key.
__device__ __forceinline__ unsigned long long wave_max_u64_dpp(unsigned long long k) {
#define FPS_STEP(ctrl)                                                         \
  {                                                                            \
    int klo = (int)(unsigned)k, khi = (int)(unsigned)(k >> 32);                \
    int olo = __builtin_amdgcn_update_dpp(klo, klo, ctrl, 0xf, 0xf, false);    \
    int ohi = __builtin_amdgcn_update_dpp(khi, khi, ctrl, 0xf, 0xf, false);    \
    unsigned long long ok =                                                    \
        ((unsigned long long)(unsigned)ohi << 32) | (unsigned)olo;             \
    if (ok > k) k = ok;                                                        \
  }
  FPS_STEP(0x111)  // row_shr:1
  FPS_STEP(0x112)  // row_shr:2
  FPS_STEP(0x114)  // row_shr:4
  FPS_STEP(0x118)  // row_shr:8
  FPS_STEP(0x142)  // row_bcast:15
  FPS_STEP(0x143)  // row_bcast:31
#undef FPS_STEP
  return k;
}

// LDS memory map (exactly 160 KiB):
//   [0,      131072) spt   : float4{x,y,z, bitcast lowk}[8192], TRANSPOSED:
//                            sorted p -> phys = (p&127)*64 + (p>>7)
//                            (lane-major: simultaneous per-cluster access has
//                             16B lane stride -> conflict-free)
//   [131072, 163840) d     : float[8192], indexed by phys (4B lane stride)
//   overlays inside the d region, consumed BEFORE wave0 initializes d:
//   [131072, 147456) sph   : float4{cx,cy,cz,rad}[1024]
//   [147456, 149504) hist  : int[512]
//   [149504, 151552) boff  : int[512]
//   [151552, 151568) wsum  : int[4]
#define SPT_OFF  0
#define D_OFF    131072
#define SPH_OFF  131072
#define HIST_OFF 147456
#define BOFF_OFF 149504
#define WSUM_OFF 151552

// ---------------------------------------------------------------------------
// 1) Furthest point sampling: SINGLE-WAVE barrier-free main loop, exact
//    two-level pruning, packed-u64-key argmax, d[] in LDS (no spills),
//    lane-major transposed layout (no bank conflicts).
//    Block = 256 thr per batch: setup (sort + cluster spheres) uses 4 waves,
//    then waves 1-3 exit; wave 0 owns all 8192 pts (128/lane = 16 clusters
//    of 8 spatially-contiguous sorted pts) and runs the 2047-step loop
//    wave-synchronously: super-sphere test (VGPR) -> masked per-cluster
//    tests -> dirty clusters re-read coords/d from LDS, exact-min update,
//    repack keys -> DPP u64 wave max -> readlane pos -> uniform b128 winner
//    fetch -> lane0 global store.
//    Key = (d_bits<<26)|(8191-pid)<<13|phys: u64 max == (max d, min ORIGINAL
//    index) == jnp.argmax first-occurrence (pid unique -> deterministic
//    despite nondeterministic scatter order). Skip thresholds conservative
//    ((sqrt(bd*1.0001)+rad)^2): skipped groups provably unchanged -> d stays
//    bit-exact vs reference.
// ---------------------------------------------------------------------------
__global__ __launch_bounds__(256, 1) void fps_kernel(const float* __restrict__ xyz,
                                                     float* __restrict__ new_xyz) {
  __shared__ __align__(16) unsigned char ldsbuf[163840];
  float4* spt  = (float4*)(ldsbuf + SPT_OFF);
  float*  dl   = (float*)(ldsbuf + D_OFF);
  float4* sph  = (float4*)(ldsbuf + SPH_OFF);
  int*    hist = (int*)(ldsbuf + HIST_OFF);
  int*    boff = (int*)(ldsbuf + BOFF_OFF);
  int*    wsum = (int*)(ldsbuf + WSUM_OFF);

  const int b = blockIdx.x;
  const int t = threadIdx.x;
  const int lane = t & 63;
  const int w = t >> 6;
  const float* xb = xyz + (size_t)b * N_ * 3;

  // ---- counting sort by 8^3 morton cell (256 threads, 32 pts each) ----
  for (int i = t; i < 512; i += 256) hist[i] = 0;
  __syncthreads();
#pragma unroll
  for (int rr = 0; rr < 32; ++rr) {
    int i = rr * 256 + t;
    float X = xb[i * 3 + 0], Y = xb[i * 3 + 1], Z = xb[i * 3 + 2];
    int ix = min(7, max(0, (int)(X * 8.0f)));
    int iy = min(7, max(0, (int)(Y * 8.0f)));
    int iz = min(7, max(0, (int)(Z * 8.0f)));
    atomicAdd(&hist[morton8(ix, iy, iz)], 1);
  }
  __syncthreads();
  // exclusive scan of 512 bins: 2 bins/thread, wave scan + wave offsets
  {
    int v0 = hist[2 * t], v1 = hist[2 * t + 1];
    int pair = v0 + v1;
    int v = pair;
#pragma unroll
    for (int off = 1; off < 64; off <<= 1) {
      int n = __shfl_up(v, off);
      if (lane >= off) v += n;
    }
    if (lane == 63) wsum[w] = v;
    __syncthreads();
    int woff = 0;
#pragma unroll
    for (int j = 0; j < 4; ++j) woff += (j < w) ? wsum[j] : 0;
    int excl = woff + v - pair;
    boff[2 * t] = excl;
    boff[2 * t + 1] = excl + v0;
  }
  __syncthreads();
  // scatter into TRANSPOSED layout; precompute key low bits into .w
#pragma unroll
  for (int rr = 0; rr < 32; ++rr) {
    int i = rr * 256 + t;
    float X = xb[i * 3 + 0], Y = xb[i * 3 + 1], Z = xb[i * 3 + 2];
    int ix = min(7, max(0, (int)(X * 8.0f)));
    int iy = min(7, max(0, (int)(Y * 8.0f)));
    int iz = min(7, max(0, (int)(Z * 8.0f)));
    int pos = atomicAdd(&boff[morton8(ix, iy, iz)], 1);
    int ph = ((pos & 127) << 6) | (pos >> 7);
    unsigned lowk = ((unsigned)(8191 - i) << 13) | (unsigned)ph;
    float4 v4; v4.x = X; v4.y = Y; v4.z = Z; v4.w = __int_as_float((int)lowk);
    spt[ph] = v4;
  }
  __syncthreads();
  // ---- cluster spheres: cluster c = sorted pts [8c, 8c+8) ----
  for (int c = t; c < 1024; c += 256) {
    float cx = 0.f, cy = 0.f, cz = 0.f;
    float qx[8], qy[8], qz[8];
#pragma unroll
    for (int k = 0; k < 8; ++k) {
      int p = c * 8 + k;
      int ph = ((p & 127) << 6) | (p >> 7);
      float4 q = spt[ph];
      qx[k] = q.x; qy[k] = q.y; qz[k] = q.z;
      cx += q.x; cy += q.y; cz += q.z;
    }
    cx *= 0.125f; cy *= 0.125f; cz *= 0.125f;
    float r2m = 0.f;
#pragma unroll
    for (int k = 0; k < 8; ++k) {
      float dx = qx[k] - cx, dy = qy[k] - cy, dz = qz[k] - cz;
      r2m = fmaxf(r2m, dx * dx + dy * dy + dz * dz);
    }
    float4 s; s.x = cx; s.y = cy; s.z = cz;
    s.w = sqrtf(r2m) * 1.00002f + 1e-12f;
    sph[c] = s;
  }
  __syncthreads();          // final barrier; waves 1-3 exit
  if (w != 0) return;

  // ---- wave0: load 16 cluster spheres/lane (cluster c = lane*16+j) ----
  float ccx[16], ccy[16], ccz[16], crad[16];
#pragma unroll
  for (int j = 0; j < 16; ++j) {
    float4 s = sph[(lane << 4) | j];
    ccx[j] = s.x; ccy[j] = s.y; ccz[j] = s.z; crad[j] = s.w;
  }
  // per-lane super-sphere over its 16 clusters
  float sxc = 0.f, syc = 0.f, szc = 0.f;
#pragma unroll
  for (int j = 0; j < 16; ++j) { sxc += ccx[j]; syc += ccy[j]; szc += ccz[j]; }
  sxc *= 0.0625f; syc *= 0.0625f; szc *= 0.0625f;
  float rs = 0.f;
#pragma unroll
  for (int j = 0; j < 16; ++j) {
    float dx = ccx[j] - sxc, dy = ccy[j] - syc, dz = ccz[j] - szc;
    rs = fmaxf(rs, sqrtf(dx * dx + dy * dy + dz * dz) + crad[j]);
  }
  rs = rs * 1.00002f + 1e-12f;

  // ---- init d AFTER spheres are consumed (overlaid region) ----
#pragma unroll
  for (int i = 0; i < 128; ++i) dl[(i << 6) | lane] = 1e10f;  // == f32(1e10)

  unsigned long long ckey[16];
  float cthr[16];
#pragma unroll
  for (int j = 0; j < 16; ++j) { ckey[j] = 0ull; cthr[j] = 3e38f; }
  unsigned long long tkey = 0ull;
  float thrS = 3e38f;

  float lx = xb[0], ly = xb[1], lz = xb[2];  // first selected index = 0
  float* outw = new_xyz + (size_t)b * M_ * 3;
  if (lane == 0) { outw[0] = lx; outw[1] = ly; outw[2] = lz; }

  for (int it = 1; it < M_; ++it) {
    float ex = lx - sxc, ey = ly - syc, ez = lz - szc;
    float dc2s = ex * ex + ey * ey + ez * ez;
    bool sd = dc2s <= thrS;
    if (__ballot(sd) != 0ull) {
      if (sd) {
#pragma unroll
        for (int j = 0; j < 16; ++j) {
          float fx = lx - ccx[j], fy = ly - ccy[j], fz = lz - ccz[j];
          float dcc = fx * fx + fy * fy + fz * fz;
          if (dcc <= cthr[j]) {
            unsigned long long nk = 0ull;
#pragma unroll
            for (int k = 0; k < 8; ++k) {
              int ph = ((j * 8 + k) << 6) | lane;   // conflict-free access
              float4 p = spt[ph];
              float dist = sqdist_rn(p.x, p.y, p.z, lx, ly, lz);
              float dm = fminf(dl[ph], dist);
              dl[ph] = dm;
              unsigned long long key =
                  ((unsigned long long)(unsigned)__float_as_int(dm) << 26) |
                  (unsigned)__float_as_int(p.w);
              nk = (key > nk) ? key : nk;
            }
            ckey[j] = nk;
            float bd = __int_as_float((int)(unsigned)(nk >> 26));
            float sr = sqrtf(bd * 1.0001f) + crad[j];  // conservative margin
            cthr[j] = sr * sr;
          }
        }
        unsigned long long nt = ckey[0];
#pragma unroll
        for (int j = 1; j < 16; ++j) nt = (ckey[j] > nt) ? ckey[j] : nt;
        tkey = nt;
        float bdS = __int_as_float((int)(unsigned)(tkey >> 26));
        float srS = sqrtf(bdS * 1.0001f) + rs;
        thrS = srS * srS;
      }
    }
    // ---- wave argmax + winner coord fetch (no barriers) ----
    unsigned long long wk = wave_max_u64_dpp(tkey);
    int winPos = __builtin_amdgcn_readlane((int)(unsigned)wk, 63) & 8191;
    float4 c = spt[winPos];  // wave-uniform addr -> broadcast b128
    lx = c.x; ly = c.y; lz = c.z;
    if (lane == 0) {
      outw[it * 3 + 0] = lx;
      outw[it * 3 + 1] = ly;
      outw[it * 3 + 2] = lz;
    }
  }
}

// ---------------------------------------------------------------------------
// 2) Fused ball-query + grouping + MLP(67->128 relu ->256) + max over K.
//    One block (256 thr) per centroid. Ball query: wave w scans index chunk
//    [w*2048,(w+1)*2048) in order, ballot-appends first <=32 valid to its own
//    LDS list; lists concat in wave order == global index order (pointnet2
//    first-K semantics). Writes pre-BN pooled features TRANSPOSED into the
//    final (B,C2,M) output region (no scratch needed).
// ---------------------------------------------------------------------------
__global__ __launch_bounds__(256) void mlp_kernel(const float* __restrict__ xyz,
                                                  const float* __restrict__ x,
                                                  const float* __restrict__ W1,
                                                  const float* __restrict__ b1,
                                                  const float* __restrict__ W2,
                                                  const float* __restrict__ b2,
                                                  const float* __restrict__ new_xyz,
                                                  float* __restrict__ outp) {
  __shared__ float sGRed[32 * 69];   // group tile; unioned w/ 8x256 max-red
  __shared__ float sU[128 * 69];     // W1 staged; unioned w/ 32x256 W2 tile
  __shared__ float sH1[32 * 132];
  __shared__ int sWIdx[4][K_];
  __shared__ int sWCnt[4];
  __shared__ int sIdx[K_];
  __shared__ float sQ[3];

  const int gm = blockIdx.x;
  const int b = gm >> 11;    // M_ = 2048
  const int m = gm & 2047;
  const int t = threadIdx.x;
  const int lane = t & 63;
  const int w = t >> 6;
  const float* xb = xyz + (size_t)b * N_ * 3;

  if (t < 3) sQ[t] = new_xyz[(size_t)gm * 3 + t];
  __syncthreads();
  const float qx = sQ[0], qy = sQ[1], qz = sQ[2];
  // (float)(0.1*0.1) = 0x3C23D70A; 0.1f*0.1f rounds differently — wrong.
  const float R2 = (float)(0.1 * 0.1);

  // ---- ball query ----
  {
    int cnt = 0;
    const int cbeg = w * 2048, cend = cbeg + 2048;
    for (int base = cbeg; base < cend; base += 64) {
      int p = base + lane;
      float d2 = sqdist_rn(qx, qy, qz, xb[p * 3 + 0], xb[p * 3 + 1], xb[p * 3 + 2]);
      bool valid = d2 < R2;
      unsigned long long mask = __ballot(valid);
      if (valid) {
        int pos = cnt + __popcll(mask & ((1ull << lane) - 1ull));
        if (pos < K_) sWIdx[w][pos] = p;
      }
      cnt += __popcll(mask);
      if (cnt >= K_) break;  // wave-uniform
    }
    if (lane == 0) sWCnt[w] = (cnt < K_) ? cnt : K_;
  }
  __syncthreads();
  if (t < K_) {
    int c0 = sWCnt[0], c1 = sWCnt[1], c2 = sWCnt[2], c3 = sWCnt[3];
    int s1 = c0 + c1, s2 = s1 + c2, s3 = s2 + c3;
    int j = t, idx;
    if (j < c0) idx = sWIdx[0][j];
    else if (j < s1) idx = sWIdx[1][j - c0];
    else if (j < s2) idx = sWIdx[2][j - s1];
    else if (j < s3) idx = sWIdx[3][j - s2];
    else {
      int fw = c0 ? 0 : (c1 ? 1 : (c2 ? 2 : 3));
      idx = (s3 > 0) ? sWIdx[fw][0] : 0;  // fill with first valid index
    }
    sIdx[j] = idx;
  }
  __syncthreads();

  // ---- grouping: rel coords + features into sGRed (32 x 69 padded) ----
  if (t < K_) {
    int id = sIdx[t];
    sGRed[t * 69 + 0] = xb[id * 3 + 0] - qx;
    sGRed[t * 69 + 1] = xb[id * 3 + 1] - qy;
    sGRed[t * 69 + 2] = xb[id * 3 + 2] - qz;
  }
  {
    int r = t & 31;
    int c0 = (t >> 5) * 8;
    int id = sIdx[r];
    const float* xf = x + ((size_t)b * C0_ + c0) * N_ + id;
#pragma unroll
    for (int j = 0; j < 8; ++j) sGRed[r * 69 + 3 + c0 + j] = xf[(size_t)j * N_];
  }
  for (int i = t; i < C1_ * CIN_; i += 256) {
    sU[(i / CIN_) * 69 + (i % CIN_)] = W1[i];
  }
  __syncthreads();

  const int ol = t & 31;  // output-lane: o = ol + 32*j
  const int rg = t >> 5;  // row group: rows rg*4 .. rg*4+3

  // ---- layer 1: h1 = relu(G @ W1^T + b1), 4 rows x 4 outs per thread ----
  float acc[4][4] = {{0.f}};
  for (int c = 0; c < CIN_; ++c) {
    float g[4], wv[4];
#pragma unroll
    for (int i = 0; i < 4; ++i) g[i] = sGRed[(rg * 4 + i) * 69 + c];
#pragma unroll
    for (int j = 0; j < 4; ++j) wv[j] = sU[(ol + 32 * j) * 69 + c];
#pragma unroll
    for (int i = 0; i < 4; ++i)
#pragma unroll
      for (int j = 0; j < 4; ++j) acc[i][j] += g[i] * wv[j];
  }
#pragma unroll
  for (int j = 0; j < 4; ++j) {
    float bias = b1[ol + 32 * j];
#pragma unroll
    for (int i = 0; i < 4; ++i) {
      float v = acc[i][j] + bias;
      sH1[(rg * 4 + i) * 132 + ol + 32 * j] = fmaxf(v, 0.0f);
    }
  }

  // ---- layer 2: h2 = h1 @ W2^T, 4 rows x 8 outs per thread ----
  float acc2[4][8] = {{0.f}};
  for (int ct = 0; ct < 4; ++ct) {
    __syncthreads();  // sU reuse safe; (ct==0) also covers sH1 writes
    const float4* w4 = (const float4*)(W2 + (size_t)t * C1_ + ct * 32);
#pragma unroll
    for (int jj = 0; jj < 8; ++jj) {
      float4 v = w4[jj];
      sU[(jj * 4 + 0) * 256 + t] = v.x;
      sU[(jj * 4 + 1) * 256 + t] = v.y;
      sU[(jj * 4 + 2) * 256 + t] = v.z;
      sU[(jj * 4 + 3) * 256 + t] = v.w;
    }
    __syncthreads();
    for (int cc = 0; cc < 32; ++cc) {
      float h[4], wv[8];
#pragma unroll
      for (int i = 0; i < 4; ++i) h[i] = sH1[(rg * 4 + i) * 132 + ct * 32 + cc];
#pragma unroll
      for (int j = 0; j < 8; ++j) wv[j] = sU[cc * 256 + ol + 32 * j];
#pragma unroll
      for (int i = 0; i < 4; ++i)
#pragma unroll
        for (int j = 0; j < 8; ++j) acc2[i][j] += h[i] * wv[j];
    }
  }

  // ---- max over K, + b2 (max(x)+c == max(x+c): RN is monotone) ----
  __syncthreads();  // group tile dead; reuse sGRed as reduction buffer
#pragma unroll
  for (int j = 0; j < 8; ++j) {
    float pm = acc2[0][j];
#pragma unroll
    for (int i = 1; i < 4; ++i) pm = fmaxf(pm, acc2[i][j]);
    sGRed[rg * 256 + ol + 32 * j] = pm;
  }
  __syncthreads();
  {
    int o = t;
    float v = sGRed[o];
#pragma unroll
    for (int g = 1; g < 8; ++g) v = fmaxf(v, sGRed[g * 256 + o]);
    v += b2[o];
    // transposed store into final (B, C2, M) layout (pre-BN)
    outp[((size_t)(b * C2_ + o)) * M_ + m] = v;
  }
}

// ---------------------------------------------------------------------------
// 3) BN stats per channel (deterministic, double accum). One block / channel.
// ---------------------------------------------------------------------------
__global__ __launch_bounds__(256) void bn_stats_kernel(const float* __restrict__ outp,
                                                       const float* __restrict__ gamma,
                                                       float* __restrict__ stats) {
  const int o = blockIdx.x;
  const int t = threadIdx.x;
  double s = 0.0, s2 = 0.0;
  for (int b = 0; b < B_; ++b) {
    const float* p = outp + ((size_t)(b * C2_ + o)) * M_;
    for (int i = t; i < M_; i += 256) {
      float v = p[i];
      s += (double)v;
      s2 += (double)v * (double)v;
    }
  }
#pragma unroll
  for (int off = 32; off > 0; off >>= 1) {
    s += __shfl_xor(s, off);
    s2 += __shfl_xor(s2, off);
  }
  __shared__ double aS[4], aS2[4];
  if ((t & 63) == 0) { aS[t >> 6] = s; aS2[t >> 6] = s2; }
  __syncthreads();
  if (t == 0) {
    double S = aS[0] + aS[1] + aS[2] + aS[3];
    double S2 = aS2[0] + aS2[1] + aS2[2] + aS2[3];
    double mean = S / (double)(B_ * M_);
    double var = S2 / (double)(B_ * M_) - mean * mean;
    float rstd = 1.0f / sqrtf((float)var + 1e-5f);
    stats[o] = (float)mean;
    stats[C2_ + o] = gamma[o] * rstd;
  }
}

// ---------------------------------------------------------------------------
// 4) BN apply, in place on the (B,C2,M) output region. float4-vectorized.
// ---------------------------------------------------------------------------
__global__ __launch_bounds__(256) void bn_apply_kernel(float* __restrict__ outp,
                                                       const float* __restrict__ stats,
                                                       const float* __restrict__ beta) {
  const int i4 = blockIdx.x * 256 + threadIdx.x;  // B_*C2_*M_/4 = 262144
  const int ch = (i4 >> 9) & 255;                 // M_/4 = 512 float4 / chan
  const float mean = stats[ch];
  const float scale = stats[C2_ + ch];
  const float bt = beta[ch];
  float4 v = ((const float4*)outp)[i4];
  v.x = (v.x - mean) * scale + bt;
  v.y = (v.y - mean) * scale + bt;
  v.z = (v.z - mean) * scale + bt;
  v.w = (v.w - mean) * scale + bt;
  ((float4*)outp)[i4] = v;
}

// ---------------------------------------------------------------------------
extern "C" void kernel_launch(void* const* d_in, const int* in_sizes, int n_in,
                              void* d_out, int out_size, void* d_ws, size_t ws_size,
                              hipStream_t stream) {
  const float* xyz   = (const float*)d_in[0];
  const float* x     = (const float*)d_in[1];
  const float* W1    = (const float*)d_in[2];
  const float* b1    = (const float*)d_in[3];
  const float* W2    = (const float*)d_in[4];
  const float* b2    = (const float*)d_in[5];
  const float* gamma = (const float*)d_in[6];
  const float* beta  = (const float*)d_in[7];

  float* new_xyz = (float*)d_out;                       // (B, M, 3)
  float* outp    = (float*)d_out + (size_t)B_ * M_ * 3; // (B, C2, M)
  float* stats   = (float*)d_ws;                        // 2*C2 floats = 2 KB

  fps_kernel<<<B_, 256, 0, stream>>>(xyz, new_xyz);
  mlp_kernel<<<B_ * M_, 256, 0, stream>>>(xyz, x, W1, b1, W2, b2, new_xyz, outp);
  bn_stats_kernel<<<C2_, 256, 0, stream>>>(outp, gamma, stats);
  bn_apply_kernel<<<(B_ * C2_ * M_ / 4) / 256, 256, 0, stream>>>(outp, stats, beta);
}

// Round 9
// 3739.889 us; speedup vs baseline: 5.5004x; 5.5004x over previous
//
#include <hip/hip_runtime.h>
#include <cstdint>
#include <cstddef>

#define B_   2
#define N_   8192
#define M_   2048
#define K_   32
#define C0_  64
#define C1_  128
#define C2_  256
#define CIN_ 67

// Exact-match distance: reference computes sum((a-b)**2, axis=-1) in f32 as
// ((dx^2 + dy^2) + dz^2) with no FMA contraction. _rn intrinsics forbid
// contract-fast fma fusion (would flip argmax / radius-boundary decisions).
__device__ __forceinline__ float sqdist_rn(float ax, float ay, float az,
                                           float bx, float by, float bz) {
  float dx = __fsub_rn(ax, bx);
  float dy = __fsub_rn(ay, by);
  float dz = __fsub_rn(az, bz);
  return __fadd_rn(__fadd_rn(__fmul_rn(dx, dx), __fmul_rn(dy, dy)),
                   __fmul_rn(dz, dz));
}

__device__ __forceinline__ int morton8(int ix, int iy, int iz) {
  int m = 0;
#pragma unroll
  for (int b = 0; b < 3; ++b) {
    m |= (((ix >> b) & 1) << (3 * b + 2)) | (((iy >> b) & 1) << (3 * b + 1)) |
         (((iz >> b) & 1) << (3 * b + 0));
  }
  return m;
}

// u64 max across the wave via paired DPP (row_shr 1/2/4/8, row_bcast 15/31);
// cumulative max lands in lane 63. Exact tie-break baked into the key.
__device__ __forceinline__ unsigned long long wave_max_u64_dpp(unsigned long long k) {
#define FPS_STEP(ctrl)                                                         \
  {                                                                            \
    int klo = (int)(unsigned)k, khi = (int)(unsigned)(k >> 32);                \
    int olo = __builtin_amdgcn_update_dpp(klo, klo, ctrl, 0xf, 0xf, false);    \
    int ohi = __builtin_amdgcn_update_dpp(khi, khi, ctrl, 0xf, 0xf, false);    \
    unsigned long long ok =                                                    \
        ((unsigned long long)(unsigned)ohi << 32) | (unsigned)olo;             \
    if (ok > k) k = ok;                                                        \
  }
  FPS_STEP(0x111)  // row_shr:1
  FPS_STEP(0x112)  // row_shr:2
  FPS_STEP(0x114)  // row_shr:4
  FPS_STEP(0x118)  // row_shr:8
  FPS_STEP(0x142)  // row_bcast:15
  FPS_STEP(0x143)  // row_bcast:31
#undef FPS_STEP
  return k;
}

// LDS map (155712 B total):
//   [0,      131072) spt     float4{x,y,z,bitcast lowk}[8192], point p of
//                            cluster c at index (k<<10)+c  (k=p&7, c=p>>3):
//                            per-body access (k<<10)+base+lane is 64 lanes
//                            x contiguous 16B -> conflict-free.
//   [131072, 147456) union:  hist[512] / boff[512] / wsum[4]  (sort phase)
//                            then sph float4{cx,cy,cz,rad}[1024] (sphere phase)
//   [147456, 155648) snewIdx int[2048]  winner phys ring (coords dumped at end)
//   [155648, 155712) sKeyP   u64[2][4]  parity-buffered per-wave key slots
// ---------------------------------------------------------------------------
// 1) FPS: 4 waves (1/SIMD), exact cluster pruning, packed-u64-key argmax,
//    ONE barrier/iter, replicated (free) winner selection.
//    Slot j of wave w = contiguous 64-cluster span [w*256+j*64, +64):
//    a spatially-local dirty set usually activates ~1 of the 16 bodies.
//    Key = (d_bits<<26)|(8191-pid)<<13|phys -> u64 max == (max d, min
//    ORIGINAL idx) == jnp.argmax first-occurrence; phys gives 1-read coord
//    fetch. Skip thresholds conservative ((sqrt(bd*1.0001)+rad)^2): skipped
//    clusters provably unchanged -> d bit-exact vs reference. Counting-sort
//    scatter order nondeterministic but output-invariant.
// ---------------------------------------------------------------------------
__global__ __launch_bounds__(256, 1) void fps_kernel(const float* __restrict__ xyz,
                                                     float* __restrict__ new_xyz) {
  __shared__ __align__(16) unsigned char ldsbuf[155712];
  float4* spt  = (float4*)(ldsbuf);
  int*    hist = (int*)(ldsbuf + 131072);
  int*    boff = (int*)(ldsbuf + 133120);
  int*    wsum = (int*)(ldsbuf + 135168);
  float4* sph  = (float4*)(ldsbuf + 131072);   // overlays hist/boff after sort
  int*    snewIdx = (int*)(ldsbuf + 147456);
  unsigned long long* sKeyP = (unsigned long long*)(ldsbuf + 155648);

  const int b = blockIdx.x;
  const int t = threadIdx.x;
  const int lane = t & 63;
  const int w = t >> 6;
  const float* xb = xyz + (size_t)b * N_ * 3;

  // ---- counting sort by 8^3 morton cell (256 threads, 32 pts each) ----
  for (int i = t; i < 512; i += 256) hist[i] = 0;
  __syncthreads();
#pragma unroll
  for (int rr = 0; rr < 32; ++rr) {
    int i = rr * 256 + t;
    float X = xb[i * 3 + 0], Y = xb[i * 3 + 1], Z = xb[i * 3 + 2];
    int ix = min(7, max(0, (int)(X * 8.0f)));
    int iy = min(7, max(0, (int)(Y * 8.0f)));
    int iz = min(7, max(0, (int)(Z * 8.0f)));
    atomicAdd(&hist[morton8(ix, iy, iz)], 1);
  }
  __syncthreads();
  // exclusive scan of 512 bins: 2 bins/thread, wave scan + wave offsets
  {
    int v0 = hist[2 * t], v1 = hist[2 * t + 1];
    int pair = v0 + v1;
    int v = pair;
#pragma unroll
    for (int off = 1; off < 64; off <<= 1) {
      int n = __shfl_up(v, off);
      if (lane >= off) v += n;
    }
    if (lane == 63) wsum[w] = v;
    __syncthreads();
    int woff = 0;
#pragma unroll
    for (int j = 0; j < 4; ++j) woff += (j < w) ? wsum[j] : 0;
    int excl = woff + v - pair;
    boff[2 * t] = excl;
    boff[2 * t + 1] = excl + v0;
  }
  __syncthreads();
  // scatter: point at sorted pos -> phys = (pos&7)*1024 + (pos>>3)
#pragma unroll
  for (int rr = 0; rr < 32; ++rr) {
    int i = rr * 256 + t;
    float X = xb[i * 3 + 0], Y = xb[i * 3 + 1], Z = xb[i * 3 + 2];
    int ix = min(7, max(0, (int)(X * 8.0f)));
    int iy = min(7, max(0, (int)(Y * 8.0f)));
    int iz = min(7, max(0, (int)(Z * 8.0f)));
    int pos = atomicAdd(&boff[morton8(ix, iy, iz)], 1);
    int ph = ((pos & 7) << 10) | (pos >> 3);
    unsigned lowk = ((unsigned)(8191 - i) << 13) | (unsigned)ph;
    float4 v4; v4.x = X; v4.y = Y; v4.z = Z; v4.w = __int_as_float((int)lowk);
    spt[ph] = v4;
    if (i == 0) snewIdx[0] = ph;  // first selected index = original 0
  }
  __syncthreads();
  // ---- cluster spheres (hist/boff dead; sph overlays them) ----
  for (int c = t; c < 1024; c += 256) {
    float cx = 0.f, cy = 0.f, cz = 0.f;
    float qx[8], qy[8], qz[8];
#pragma unroll
    for (int k = 0; k < 8; ++k) {
      float4 q = spt[(k << 10) | c];
      qx[k] = q.x; qy[k] = q.y; qz[k] = q.z;
      cx += q.x; cy += q.y; cz += q.z;
    }
    cx *= 0.125f; cy *= 0.125f; cz *= 0.125f;
    float r2m = 0.f;
#pragma unroll
    for (int k = 0; k < 8; ++k) {
      float dx = qx[k] - cx, dy = qy[k] - cy, dz = qz[k] - cz;
      r2m = fmaxf(r2m, dx * dx + dy * dy + dz * dz);
    }
    float4 s; s.x = cx; s.y = cy; s.z = cz;
    s.w = sqrtf(r2m) * 1.00002f + 1e-12f;
    sph[c] = s;
  }
  __syncthreads();

  // ---- per-thread state: 4 clusters (slot j -> cluster w*256+j*64+lane) ----
  float csx[4], csy[4], csz[4], crad[4];
#pragma unroll
  for (int j = 0; j < 4; ++j) {
    float4 s = sph[(w << 8) | (j << 6) | lane];
    csx[j] = s.x; csy[j] = s.y; csz[j] = s.z; crad[j] = s.w;
  }
  float d[32];
#pragma unroll
  for (int i = 0; i < 32; ++i) d[i] = 1e10f;  // == f32(1e10), matches jnp
  unsigned long long ckey[4] = {0ull, 0ull, 0ull, 0ull};
  float cthr[4] = {3e38f, 3e38f, 3e38f, 3e38f};

  float lx = xb[0], ly = xb[1], lz = xb[2];

  for (int it = 1; it < M_; ++it) {
    const int wp = it & 1;
    // ---- per-slot skip tests + exec-masked dirty bodies ----
#pragma unroll
    for (int j = 0; j < 4; ++j) {
      float fx = lx - csx[j], fy = ly - csy[j], fz = lz - csz[j];
      float dcc = fx * fx + fy * fy + fz * fz;
      if (dcc <= cthr[j]) {
        const int cbase = (w << 8) | (j << 6) | lane;
        unsigned long long nk = 0ull;
#pragma unroll
        for (int k = 0; k < 8; ++k) {
          float4 p = spt[(k << 10) | cbase];
          float dist = sqdist_rn(p.x, p.y, p.z, lx, ly, lz);
          float dm = fminf(d[j * 8 + k], dist);
          d[j * 8 + k] = dm;
          unsigned long long key =
              ((unsigned long long)(unsigned)__float_as_int(dm) << 26) |
              (unsigned)__float_as_int(p.w);
          nk = (key > nk) ? key : nk;
        }
        ckey[j] = nk;
        float bd = __int_as_float((int)(unsigned)(nk >> 26));
        float sr = sqrtf(bd * 1.0001f) + crad[j];  // conservative margin
        cthr[j] = sr * sr;
      }
    }
    unsigned long long tk = ckey[0];
    tk = (ckey[1] > tk) ? ckey[1] : tk;
    tk = (ckey[2] > tk) ? ckey[2] : tk;
    tk = (ckey[3] > tk) ? ckey[3] : tk;
    unsigned long long wk = wave_max_u64_dpp(tk);
    if (lane == 63) sKeyP[wp * 4 + w] = wk;
    __syncthreads();  // the ONLY barrier (parity buffer fences next write)
    // ---- replicated winner selection (1 wave/SIMD -> free) ----
    {
      const ulonglong2* sk = (const ulonglong2*)(sKeyP + wp * 4);
      ulonglong2 a = sk[0];   // broadcast b128
      ulonglong2 c2 = sk[1];  // broadcast b128
      unsigned long long m0 = (a.x > a.y) ? a.x : a.y;
      unsigned long long m1 = (c2.x > c2.y) ? c2.x : c2.y;
      unsigned long long win = (m0 > m1) ? m0 : m1;
      int winPos = (int)((unsigned)win & 8191u);
      float4 cw = spt[winPos];  // wave-uniform addr -> broadcast b128
      lx = cw.x; ly = cw.y; lz = cw.z;
      if (t == 0) snewIdx[it] = winPos;
    }
  }
  __syncthreads();  // final snewIdx write visible

  // ---- dump winner coords in selection order ----
  for (int i = t; i < M_; i += 256) {
    float4 p = spt[snewIdx[i]];
    float* o = new_xyz + (size_t)b * M_ * 3 + (size_t)i * 3;
    o[0] = p.x; o[1] = p.y; o[2] = p.z;
  }
}

// ---------------------------------------------------------------------------
// 2) Fused ball-query + grouping + MLP(67->128 relu ->256) + max over K.
//    One block (256 thr) per centroid. Ball query: wave w scans index chunk
//    [w*2048,(w+1)*2048) in order, ballot-appends first <=32 valid to its own
//    LDS list; lists concat in wave order == global index order (pointnet2
//    first-K semantics). Writes pre-BN pooled features TRANSPOSED into the
//    final (B,C2,M) output region (no scratch needed).
// ---------------------------------------------------------------------------
__global__ __launch_bounds__(256) void mlp_kernel(const float* __restrict__ xyz,
                                                  const float* __restrict__ x,
                                                  const float* __restrict__ W1,
                                                  const float* __restrict__ b1,
                                                  const float* __restrict__ W2,
                                                  const float* __restrict__ b2,
                                                  const float* __restrict__ new_xyz,
                                                  float* __restrict__ outp) {
  __shared__ float sGRed[32 * 69];   // group tile; unioned w/ 8x256 max-red
  __shared__ float sU[128 * 69];     // W1 staged; unioned w/ 32x256 W2 tile
  __shared__ float sH1[32 * 132];
  __shared__ int sWIdx[4][K_];
  __shared__ int sWCnt[4];
  __shared__ int sIdx[K_];
  __shared__ float sQ[3];

  const int gm = blockIdx.x;
  const int b = gm >> 11;    // M_ = 2048
  const int m = gm & 2047;
  const int t = threadIdx.x;
  const int lane = t & 63;
  const int w = t >> 6;
  const float* xb = xyz + (size_t)b * N_ * 3;

  if (t < 3) sQ[t] = new_xyz[(size_t)gm * 3 + t];
  __syncthreads();
  const float qx = sQ[0], qy = sQ[1], qz = sQ[2];
  // (float)(0.1*0.1) = 0x3C23D70A; 0.1f*0.1f rounds differently — wrong.
  const float R2 = (float)(0.1 * 0.1);

  // ---- ball query ----
  {
    int cnt = 0;
    const int cbeg = w * 2048, cend = cbeg + 2048;
    for (int base = cbeg; base < cend; base += 64) {
      int p = base + lane;
      float d2 = sqdist_rn(qx, qy, qz, xb[p * 3 + 0], xb[p * 3 + 1], xb[p * 3 + 2]);
      bool valid = d2 < R2;
      unsigned long long mask = __ballot(valid);
      if (valid) {
        int pos = cnt + __popcll(mask & ((1ull << lane) - 1ull));
        if (pos < K_) sWIdx[w][pos] = p;
      }
      cnt += __popcll(mask);
      if (cnt >= K_) break;  // wave-uniform
    }
    if (lane == 0) sWCnt[w] = (cnt < K_) ? cnt : K_;
  }
  __syncthreads();
  if (t < K_) {
    int c0 = sWCnt[0], c1 = sWCnt[1], c2 = sWCnt[2], c3 = sWCnt[3];
    int s1 = c0 + c1, s2 = s1 + c2, s3 = s2 + c3;
    int j = t, idx;
    if (j < c0) idx = sWIdx[0][j];
    else if (j < s1) idx = sWIdx[1][j - c0];
    else if (j < s2) idx = sWIdx[2][j - s1];
    else if (j < s3) idx = sWIdx[3][j - s2];
    else {
      int fw = c0 ? 0 : (c1 ? 1 : (c2 ? 2 : 3));
      idx = (s3 > 0) ? sWIdx[fw][0] : 0;  // fill with first valid index
    }
    sIdx[j] = idx;
  }
  __syncthreads();

  // ---- grouping: rel coords + features into sGRed (32 x 69 padded) ----
  if (t < K_) {
    int id = sIdx[t];
    sGRed[t * 69 + 0] = xb[id * 3 + 0] - qx;
    sGRed[t * 69 + 1] = xb[id * 3 + 1] - qy;
    sGRed[t * 69 + 2] = xb[id * 3 + 2] - qz;
  }
  {
    int r = t & 31;
    int c0 = (t >> 5) * 8;
    int id = sIdx[r];
    const float* xf = x + ((size_t)b * C0_ + c0) * N_ + id;
#pragma unroll
    for (int j = 0; j < 8; ++j) sGRed[r * 69 + 3 + c0 + j] = xf[(size_t)j * N_];
  }
  for (int i = t; i < C1_ * CIN_; i += 256) {
    sU[(i / CIN_) * 69 + (i % CIN_)] = W1[i];
  }
  __syncthreads();

  const int ol = t & 31;  // output-lane: o = ol + 32*j
  const int rg = t >> 5;  // row group: rows rg*4 .. rg*4+3

  // ---- layer 1: h1 = relu(G @ W1^T + b1), 4 rows x 4 outs per thread ----
  float acc[4][4] = {{0.f}};
  for (int c = 0; c < CIN_; ++c) {
    float g[4], wv[4];
#pragma unroll
    for (int i = 0; i < 4; ++i) g[i] = sGRed[(rg * 4 + i) * 69 + c];
#pragma unroll
    for (int j = 0; j < 4; ++j) wv[j] = sU[(ol + 32 * j) * 69 + c];
#pragma unroll
    for (int i = 0; i < 4; ++i)
#pragma unroll
      for (int j = 0; j < 4; ++j) acc[i][j] += g[i] * wv[j];
  }
#pragma unroll
  for (int j = 0; j < 4; ++j) {
    float bias = b1[ol + 32 * j];
#pragma unroll
    for (int i = 0; i < 4; ++i) {
      float v = acc[i][j] + bias;
      sH1[(rg * 4 + i) * 132 + ol + 32 * j] = fmaxf(v, 0.0f);
    }
  }

  // ---- layer 2: h2 = h1 @ W2^T, 4 rows x 8 outs per thread ----
  float acc2[4][8] = {{0.f}};
  for (int ct = 0; ct < 4; ++ct) {
    __syncthreads();  // sU reuse safe; (ct==0) also covers sH1 writes
    const float4* w4 = (const float4*)(W2 + (size_t)t * C1_ + ct * 32);
#pragma unroll
    for (int jj = 0; jj < 8; ++jj) {
      float4 v = w4[jj];
      sU[(jj * 4 + 0) * 256 + t] = v.x;
      sU[(jj * 4 + 1) * 256 + t] = v.y;
      sU[(jj * 4 + 2) * 256 + t] = v.z;
      sU[(jj * 4 + 3) * 256 + t] = v.w;
    }
    __syncthreads();
    for (int cc = 0; cc < 32; ++cc) {
      float h[4], wv[8];
#pragma unroll
      for (int i = 0; i < 4; ++i) h[i] = sH1[(rg * 4 + i) * 132 + ct * 32 + cc];
#pragma unroll
      for (int j = 0; j < 8; ++j) wv[j] = sU[cc * 256 + ol + 32 * j];
#pragma unroll
      for (int i = 0; i < 4; ++i)
#pragma unroll
        for (int j = 0; j < 8; ++j) acc2[i][j] += h[i] * wv[j];
    }
  }

  // ---- max over K, + b2 (max(x)+c == max(x+c): RN is monotone) ----
  __syncthreads();  // group tile dead; reuse sGRed as reduction buffer
#pragma unroll
  for (int j = 0; j < 8; ++j) {
    float pm = acc2[0][j];
#pragma unroll
    for (int i = 1; i < 4; ++i) pm = fmaxf(pm, acc2[i][j]);
    sGRed[rg * 256 + ol + 32 * j] = pm;
  }
  __syncthreads();
  {
    int o = t;
    float v = sGRed[o];
#pragma unroll
    for (int g = 1; g < 8; ++g) v = fmaxf(v, sGRed[g * 256 + o]);
    v += b2[o];
    // transposed store into final (B, C2, M) layout (pre-BN)
    outp[((size_t)(b * C2_ + o)) * M_ + m] = v;
  }
}

// ---------------------------------------------------------------------------
// 3) BN stats per channel (deterministic, double accum). One block / channel.
// ---------------------------------------------------------------------------
__global__ __launch_bounds__(256) void bn_stats_kernel(const float* __restrict__ outp,
                                                       const float* __restrict__ gamma,
                                                       float* __restrict__ stats) {
  const int o = blockIdx.x;
  const int t = threadIdx.x;
  double s = 0.0, s2 = 0.0;
  for (int b = 0; b < B_; ++b) {
    const float* p = outp + ((size_t)(b * C2_ + o)) * M_;
    for (int i = t; i < M_; i += 256) {
      float v = p[i];
      s += (double)v;
      s2 += (double)v * (double)v;
    }
  }
#pragma unroll
  for (int off = 32; off > 0; off >>= 1) {
    s += __shfl_xor(s, off);
    s2 += __shfl_xor(s2, off);
  }
  __shared__ double aS[4], aS2[4];
  if ((t & 63) == 0) { aS[t >> 6] = s; aS2[t >> 6] = s2; }
  __syncthreads();
  if (t == 0) {
    double S = aS[0] + aS[1] + aS[2] + aS[3];
    double S2 = aS2[0] + aS2[1] + aS2[2] + aS2[3];
    double mean = S / (double)(B_ * M_);
    double var = S2 / (double)(B_ * M_) - mean * mean;
    float rstd = 1.0f / sqrtf((float)var + 1e-5f);
    stats[o] = (float)mean;
    stats[C2_ + o] = gamma[o] * rstd;
  }
}

// ---------------------------------------------------------------------------
// 4) BN apply, in place on the (B,C2,M) output region. float4-vectorized.
// ---------------------------------------------------------------------------
__global__ __launch_bounds__(256) void bn_apply_kernel(float* __restrict__ outp,
                                                       const float* __restrict__ stats,
                                                       const float* __restrict__ beta) {
  const int i4 = blockIdx.x * 256 + threadIdx.x;  // B_*C2_*M_/4 = 262144
  const int ch = (i4 >> 9) & 255;                 // M_/4 = 512 float4 / chan
  const float mean = stats[ch];
  const float scale = stats[C2_ + ch];
  const float bt = beta[ch];
  float4 v = ((const float4*)outp)[i4];
  v.x = (v.x - mean) * scale + bt;
  v.y = (v.y - mean) * scale + bt;
  v.z = (v.z - mean) * scale + bt;
  v.w = (v.w - mean) * scale + bt;
  ((float4*)outp)[i4] = v;
}

// ---------------------------------------------------------------------------
extern "C" void kernel_launch(void* const* d_in, const int* in_sizes, int n_in,
                              void* d_out, int out_size, void* d_ws, size_t ws_size,
                              hipStream_t stream) {
  const float* xyz   = (const float*)d_in[0];
  const float* x     = (const float*)d_in[1];
  const float* W1    = (const float*)d_in[2];
  const float* b1    = (const float*)d_in[3];
  const float* W2    = (const float*)d_in[4];
  const float* b2    = (const float*)d_in[5];
  const float* gamma = (const float*)d_in[6];
  const float* beta  = (const float*)d_in[7];

  float* new_xyz = (float*)d_out;                       // (B, M, 3)
  float* outp    = (float*)d_out + (size_t)B_ * M_ * 3; // (B, C2, M)
  float* stats   = (float*)d_ws;                        // 2*C2 floats = 2 KB

  fps_kernel<<<B_, 256, 0, stream>>>(xyz, new_xyz);
  mlp_kernel<<<B_ * M_, 256, 0, stream>>>(xyz, x, W1, b1, W2, b2, new_xyz, outp);
  bn_stats_kernel<<<C2_, 256, 0, stream>>>(outp, gamma, stats);
  bn_apply_kernel<<<(B_ * C2_ * M_ / 4) / 256, 256, 0, stream>>>(outp, stats, beta);
}

// Round 10
// 3178.792 us; speedup vs baseline: 6.4712x; 1.1765x over previous
//
#include <hip/hip_runtime.h>
#include <cstdint>
#include <cstddef>

#define B_   2
#define N_   8192
#define M_   2048
#define K_   32
#define C0_  64
#define C1_  128
#define C2_  256
#define CIN_ 67

// Exact-match distance: reference computes sum((a-b)**2, axis=-1) in f32 as
// ((dx^2 + dy^2) + dz^2) with no FMA contraction. _rn intrinsics forbid
// contract-fast fma fusion (would flip argmax / radius-boundary decisions).
__device__ __forceinline__ float sqdist_rn(float ax, float ay, float az,
                                           float bx, float by, float bz) {
  float dx = __fsub_rn(ax, bx);
  float dy = __fsub_rn(ay, by);
  float dz = __fsub_rn(az, bz);
  return __fadd_rn(__fadd_rn(__fmul_rn(dx, dx), __fmul_rn(dy, dy)),
                   __fmul_rn(dz, dz));
}

__device__ __forceinline__ int morton8(int ix, int iy, int iz) {
  int m = 0;
#pragma unroll
  for (int b = 0; b < 3; ++b) {
    m |= (((ix >> b) & 1) << (3 * b + 2)) | (((iy >> b) & 1) << (3 * b + 1)) |
         (((iz >> b) & 1) << (3 * b + 0));
  }
  return m;
}

// u64 max across the wave via paired DPP (row_shr 1/2/4/8, row_bcast 15/31);
// cumulative max lands in lane 63. Exact tie-break baked into the key.
__device__ __forceinline__ unsigned long long wave_max_u64_dpp(unsigned long long k) {
#define FPS_STEP(ctrl)                                                         \
  {                                                                            \
    int klo = (int)(unsigned)k, khi = (int)(unsigned)(k >> 32);                \
    int olo = __builtin_amdgcn_update_dpp(klo, klo, ctrl, 0xf, 0xf, false);    \
    int ohi = __builtin_amdgcn_update_dpp(khi, khi, ctrl, 0xf, 0xf, false);    \
    unsigned long long ok =                                                    \
        ((unsigned long long)(unsigned)ohi << 32) | (unsigned)olo;             \
    if (ok > k) k = ok;                                                        \
  }
  FPS_STEP(0x111)  // row_shr:1
  FPS_STEP(0x112)  // row_shr:2
  FPS_STEP(0x114)  // row_shr:4
  FPS_STEP(0x118)  // row_shr:8
  FPS_STEP(0x142)  // row_bcast:15
  FPS_STEP(0x143)  // row_bcast:31
#undef FPS_STEP
  return k;
}

// LDS map (155904 B):
//   [0,      131072) spt     float4{x,y,z,bitcast lowk}[8192]; sorted point
//                            p stored at phys = (p&7)*1024 + (p>>3): per-body
//                            access (k<<10)+base+lane is 64 lanes x contiguous
//                            16B -> conflict-free.
//   [131072, 147456) union:  hist[512]/boff[512]/wsum[8] (sort), then
//                            sph float4{cx,cy,cz,rad}[1024] (spheres).
//   [147456, 155648) snewIdx int[2048] winner phys ring (coords dumped at end)
//   [155648, 155904) sKeyP   u64[2][8] parity-buffered per-wave key slots
// ---------------------------------------------------------------------------
// 1) FPS: 512 thr = 8 waves = 2 waves/SIMD (latency hiding, cheap
//    replication), exact cluster pruning, packed-u64-key argmax, ONE barrier
//    per iteration, replicated winner selection by all waves.
//    Lane of wave w owns 2 Morton-contiguous clusters (w*128 + j*64 + lane,
//    j=0,1), 8 pts each; d[16] in VGPRs. Dirty bodies hoist all 8
//    ds_read_b128 before compute (one waitcnt). Clean waves skip update+DPP
//    and just rewrite their cached slot key (parity double buffer makes the
//    single barrier fence writes->reads and reads->next-writes).
//    Key = (d_bits<<26)|(8191-pid)<<13|phys -> u64 max == (max d, min
//    ORIGINAL idx) == jnp.argmax first-occurrence. Skip thresholds
//    conservative ((sqrt(bd*1.0001)+rad)^2): skipped clusters provably
//    unchanged -> d bit-exact vs reference. Counting-sort scatter order
//    nondeterministic but output-invariant.
// ---------------------------------------------------------------------------
__global__ __launch_bounds__(512, 1) void fps_kernel(const float* __restrict__ xyz,
                                                     float* __restrict__ new_xyz) {
  __shared__ __align__(16) unsigned char ldsbuf[155904];
  float4* spt  = (float4*)(ldsbuf);
  int*    hist = (int*)(ldsbuf + 131072);
  int*    boff = (int*)(ldsbuf + 133120);
  int*    wsum = (int*)(ldsbuf + 135168);
  float4* sph  = (float4*)(ldsbuf + 131072);   // overlays hist/boff after sort
  int*    snewIdx = (int*)(ldsbuf + 147456);
  unsigned long long* sKeyP = (unsigned long long*)(ldsbuf + 155648);

  const int b = blockIdx.x;
  const int t = threadIdx.x;
  const int lane = t & 63;
  const int w = t >> 6;
  const float* xb = xyz + (size_t)b * N_ * 3;

  // ---- counting sort by 8^3 morton cell (512 threads, 16 pts each) ----
  if (t < 512) hist[t] = 0;
  __syncthreads();
#pragma unroll
  for (int rr = 0; rr < 16; ++rr) {
    int i = rr * 512 + t;
    float X = xb[i * 3 + 0], Y = xb[i * 3 + 1], Z = xb[i * 3 + 2];
    int ix = min(7, max(0, (int)(X * 8.0f)));
    int iy = min(7, max(0, (int)(Y * 8.0f)));
    int iz = min(7, max(0, (int)(Z * 8.0f)));
    atomicAdd(&hist[morton8(ix, iy, iz)], 1);
  }
  __syncthreads();
  // exclusive scan of 512 bins: 1 bin/thread, wave scan + wave offsets
  {
    int ov = hist[t];
    int v = ov;
#pragma unroll
    for (int off = 1; off < 64; off <<= 1) {
      int n = __shfl_up(v, off);
      if (lane >= off) v += n;
    }
    if (lane == 63) wsum[w] = v;
    __syncthreads();
    int woff = 0;
#pragma unroll
    for (int j = 0; j < 8; ++j) woff += (j < w) ? wsum[j] : 0;
    boff[t] = woff + v - ov;
  }
  __syncthreads();
  // scatter: sorted pos -> phys = (pos&7)*1024 + (pos>>3); lowk into .w
#pragma unroll
  for (int rr = 0; rr < 16; ++rr) {
    int i = rr * 512 + t;
    float X = xb[i * 3 + 0], Y = xb[i * 3 + 1], Z = xb[i * 3 + 2];
    int ix = min(7, max(0, (int)(X * 8.0f)));
    int iy = min(7, max(0, (int)(Y * 8.0f)));
    int iz = min(7, max(0, (int)(Z * 8.0f)));
    int pos = atomicAdd(&boff[morton8(ix, iy, iz)], 1);
    int ph = ((pos & 7) << 10) | (pos >> 3);
    unsigned lowk = ((unsigned)(8191 - i) << 13) | (unsigned)ph;
    float4 v4; v4.x = X; v4.y = Y; v4.z = Z; v4.w = __int_as_float((int)lowk);
    spt[ph] = v4;
    if (i == 0) snewIdx[0] = ph;  // first selected index = original 0
  }
  __syncthreads();
  // ---- cluster spheres (hist/boff dead; sph overlays them) ----
  for (int c = t; c < 1024; c += 512) {
    float cx = 0.f, cy = 0.f, cz = 0.f;
    float qx[8], qy[8], qz[8];
#pragma unroll
    for (int k = 0; k < 8; ++k) {
      float4 q = spt[(k << 10) | c];
      qx[k] = q.x; qy[k] = q.y; qz[k] = q.z;
      cx += q.x; cy += q.y; cz += q.z;
    }
    cx *= 0.125f; cy *= 0.125f; cz *= 0.125f;
    float r2m = 0.f;
#pragma unroll
    for (int k = 0; k < 8; ++k) {
      float dx = qx[k] - cx, dy = qy[k] - cy, dz = qz[k] - cz;
      r2m = fmaxf(r2m, dx * dx + dy * dy + dz * dz);
    }
    float4 s; s.x = cx; s.y = cy; s.z = cz;
    s.w = sqrtf(r2m) * 1.00002f + 1e-12f;
    sph[c] = s;
  }
  __syncthreads();

  // ---- per-thread: 2 clusters (slot j -> cluster w*128 + j*64 + lane) ----
  float csx[2], csy[2], csz[2], crad[2];
#pragma unroll
  for (int j = 0; j < 2; ++j) {
    float4 s = sph[(w << 7) | (j << 6) | lane];
    csx[j] = s.x; csy[j] = s.y; csz[j] = s.z; crad[j] = s.w;
  }
  float d[16];
#pragma unroll
  for (int i = 0; i < 16; ++i) d[i] = 1e10f;  // == f32(1e10), matches jnp
  unsigned long long ckey[2] = {0ull, 0ull};
  float cthr[2] = {3e38f, 3e38f};
  unsigned long long wk = 0ull;  // cached wave slot key

  float lx = xb[0], ly = xb[1], lz = xb[2];

  for (int it = 1; it < M_; ++it) {
    const int wp = it & 1;
    // ---- per-slot skip tests ----
    float f0x = lx - csx[0], f0y = ly - csy[0], f0z = lz - csz[0];
    float f1x = lx - csx[1], f1y = ly - csy[1], f1z = lz - csz[1];
    bool d0 = (f0x * f0x + f0y * f0y + f0z * f0z) <= cthr[0];
    bool d1 = (f1x * f1x + f1y * f1y + f1z * f1z) <= cthr[1];
    if (__ballot(d0 || d1) != 0ull) {  // wave-uniform
#pragma unroll
      for (int j = 0; j < 2; ++j) {
        bool dirty = (j == 0) ? d0 : d1;
        if (dirty) {
          const int cbase = (w << 7) | (j << 6) | lane;
          float4 P[8];
#pragma unroll
          for (int k = 0; k < 8; ++k) P[k] = spt[(k << 10) | cbase];  // batched
          unsigned long long nk = 0ull;
#pragma unroll
          for (int k = 0; k < 8; ++k) {
            float dist = sqdist_rn(P[k].x, P[k].y, P[k].z, lx, ly, lz);
            float dm = fminf(d[j * 8 + k], dist);
            d[j * 8 + k] = dm;
            unsigned long long key =
                ((unsigned long long)(unsigned)__float_as_int(dm) << 26) |
                (unsigned)__float_as_int(P[k].w);
            nk = (key > nk) ? key : nk;
          }
          ckey[j] = nk;
          float bd = __int_as_float((int)(unsigned)(nk >> 26));
          float sr = sqrtf(bd * 1.0001f) + crad[j];  // conservative margin
          cthr[j] = sr * sr;
        }
      }
      unsigned long long tk = (ckey[0] > ckey[1]) ? ckey[0] : ckey[1];
      wk = wave_max_u64_dpp(tk);
    }
    if (lane == 63) sKeyP[wp * 8 + w] = wk;
    __syncthreads();  // the ONLY barrier (parity buffer fences next write)
    // ---- replicated winner selection (2 waves/SIMD -> cheap) ----
    {
      const ulonglong2* sk = (const ulonglong2*)(sKeyP + wp * 8);
      ulonglong2 a = sk[0], c2 = sk[1], e = sk[2], g = sk[3];  // broadcast
      unsigned long long m0 = (a.x > a.y) ? a.x : a.y;
      unsigned long long m1 = (c2.x > c2.y) ? c2.x : c2.y;
      unsigned long long m2 = (e.x > e.y) ? e.x : e.y;
      unsigned long long m3 = (g.x > g.y) ? g.x : g.y;
      m0 = (m0 > m1) ? m0 : m1;
      m2 = (m2 > m3) ? m2 : m3;
      unsigned long long win = (m0 > m2) ? m0 : m2;
      int winPos = (int)((unsigned)win & 8191u);
      float4 cw = spt[winPos];  // wave-uniform addr -> broadcast b128
      lx = cw.x; ly = cw.y; lz = cw.z;
      if (t == 0) snewIdx[it] = winPos;
    }
  }
  __syncthreads();  // final snewIdx writes visible

  // ---- dump winner coords in selection order ----
  for (int i = t; i < M_; i += 512) {
    float4 p = spt[snewIdx[i]];
    float* o = new_xyz + (size_t)b * M_ * 3 + (size_t)i * 3;
    o[0] = p.x; o[1] = p.y; o[2] = p.z;
  }
}

// ---------------------------------------------------------------------------
// 2) Fused ball-query + grouping + MLP(67->128 relu ->256) + max over K.
//    One block (256 thr) per centroid. Ball query: wave w scans index chunk
//    [w*2048,(w+1)*2048) in order, ballot-appends first <=32 valid to its own
//    LDS list; lists concat in wave order == global index order (pointnet2
//    first-K semantics). Writes pre-BN pooled features TRANSPOSED into the
//    final (B,C2,M) output region (no scratch needed).
// ---------------------------------------------------------------------------
__global__ __launch_bounds__(256) void mlp_kernel(const float* __restrict__ xyz,
                                                  const float* __restrict__ x,
                                                  const float* __restrict__ W1,
                                                  const float* __restrict__ b1,
                                                  const float* __restrict__ W2,
                                                  const float* __restrict__ b2,
                                                  const float* __restrict__ new_xyz,
                                                  float* __restrict__ outp) {
  __shared__ float sGRed[32 * 69];   // group tile; unioned w/ 8x256 max-red
  __shared__ float sU[128 * 69];     // W1 staged; unioned w/ 32x256 W2 tile
  __shared__ float sH1[32 * 132];
  __shared__ int sWIdx[4][K_];
  __shared__ int sWCnt[4];
  __shared__ int sIdx[K_];
  __shared__ float sQ[3];

  const int gm = blockIdx.x;
  const int b = gm >> 11;    // M_ = 2048
  const int m = gm & 2047;
  const int t = threadIdx.x;
  const int lane = t & 63;
  const int w = t >> 6;
  const float* xb = xyz + (size_t)b * N_ * 3;

  if (t < 3) sQ[t] = new_xyz[(size_t)gm * 3 + t];
  __syncthreads();
  const float qx = sQ[0], qy = sQ[1], qz = sQ[2];
  // (float)(0.1*0.1) = 0x3C23D70A; 0.1f*0.1f rounds differently — wrong.
  const float R2 = (float)(0.1 * 0.1);

  // ---- ball query ----
  {
    int cnt = 0;
    const int cbeg = w * 2048, cend = cbeg + 2048;
    for (int base = cbeg; base < cend; base += 64) {
      int p = base + lane;
      float d2 = sqdist_rn(qx, qy, qz, xb[p * 3 + 0], xb[p * 3 + 1], xb[p * 3 + 2]);
      bool valid = d2 < R2;
      unsigned long long mask = __ballot(valid);
      if (valid) {
        int pos = cnt + __popcll(mask & ((1ull << lane) - 1ull));
        if (pos < K_) sWIdx[w][pos] = p;
      }
      cnt += __popcll(mask);
      if (cnt >= K_) break;  // wave-uniform
    }
    if (lane == 0) sWCnt[w] = (cnt < K_) ? cnt : K_;
  }
  __syncthreads();
  if (t < K_) {
    int c0 = sWCnt[0], c1 = sWCnt[1], c2 = sWCnt[2], c3 = sWCnt[3];
    int s1 = c0 + c1, s2 = s1 + c2, s3 = s2 + c3;
    int j = t, idx;
    if (j < c0) idx = sWIdx[0][j];
    else if (j < s1) idx = sWIdx[1][j - c0];
    else if (j < s2) idx = sWIdx[2][j - s1];
    else if (j < s3) idx = sWIdx[3][j - s2];
    else {
      int fw = c0 ? 0 : (c1 ? 1 : (c2 ? 2 : 3));
      idx = (s3 > 0) ? sWIdx[fw][0] : 0;  // fill with first valid index
    }
    sIdx[j] = idx;
  }
  __syncthreads();

  // ---- grouping: rel coords + features into sGRed (32 x 69 padded) ----
  if (t < K_) {
    int id = sIdx[t];
    sGRed[t * 69 + 0] = xb[id * 3 + 0] - qx;
    sGRed[t * 69 + 1] = xb[id * 3 + 1] - qy;
    sGRed[t * 69 + 2] = xb[id * 3 + 2] - qz;
  }
  {
    int r = t & 31;
    int c0 = (t >> 5) * 8;
    int id = sIdx[r];
    const float* xf = x + ((size_t)b * C0_ + c0) * N_ + id;
#pragma unroll
    for (int j = 0; j < 8; ++j) sGRed[r * 69 + 3 + c0 + j] = xf[(size_t)j * N_];
  }
  for (int i = t; i < C1_ * CIN_; i += 256) {
    sU[(i / CIN_) * 69 + (i % CIN_)] = W1[i];
  }
  __syncthreads();

  const int ol = t & 31;  // output-lane: o = ol + 32*j
  const int rg = t >> 5;  // row group: rows rg*4 .. rg*4+3

  // ---- layer 1: h1 = relu(G @ W1^T + b1), 4 rows x 4 outs per thread ----
  float acc[4][4] = {{0.f}};
  for (int c = 0; c < CIN_; ++c) {
    float g[4], wv[4];
#pragma unroll
    for (int i = 0; i < 4; ++i) g[i] = sGRed[(rg * 4 + i) * 69 + c];
#pragma unroll
    for (int j = 0; j < 4; ++j) wv[j] = sU[(ol + 32 * j) * 69 + c];
#pragma unroll
    for (int i = 0; i < 4; ++i)
#pragma unroll
      for (int j = 0; j < 4; ++j) acc[i][j] += g[i] * wv[j];
  }
#pragma unroll
  for (int j = 0; j < 4; ++j) {
    float bias = b1[ol + 32 * j];
#pragma unroll
    for (int i = 0; i < 4; ++i) {
      float v = acc[i][j] + bias;
      sH1[(rg * 4 + i) * 132 + ol + 32 * j] = fmaxf(v, 0.0f);
    }
  }

  // ---- layer 2: h2 = h1 @ W2^T, 4 rows x 8 outs per thread ----
  float acc2[4][8] = {{0.f}};
  for (int ct = 0; ct < 4; ++ct) {
    __syncthreads();  // sU reuse safe; (ct==0) also covers sH1 writes
    const float4* w4 = (const float4*)(W2 + (size_t)t * C1_ + ct * 32);
#pragma unroll
    for (int jj = 0; jj < 8; ++jj) {
      float4 v = w4[jj];
      sU[(jj * 4 + 0) * 256 + t] = v.x;
      sU[(jj * 4 + 1) * 256 + t] = v.y;
      sU[(jj * 4 + 2) * 256 + t] = v.z;
      sU[(jj * 4 + 3) * 256 + t] = v.w;
    }
    __syncthreads();
    for (int cc = 0; cc < 32; ++cc) {
      float h[4], wv[8];
#pragma unroll
      for (int i = 0; i < 4; ++i) h[i] = sH1[(rg * 4 + i) * 132 + ct * 32 + cc];
#pragma unroll
      for (int j = 0; j < 8; ++j) wv[j] = sU[cc * 256 + ol + 32 * j];
#pragma unroll
      for (int i = 0; i < 4; ++i)
#pragma unroll
        for (int j = 0; j < 8; ++j) acc2[i][j] += h[i] * wv[j];
    }
  }

  // ---- max over K, + b2 (max(x)+c == max(x+c): RN is monotone) ----
  __syncthreads();  // group tile dead; reuse sGRed as reduction buffer
#pragma unroll
  for (int j = 0; j < 8; ++j) {
    float pm = acc2[0][j];
#pragma unroll
    for (int i = 1; i < 4; ++i) pm = fmaxf(pm, acc2[i][j]);
    sGRed[rg * 256 + ol + 32 * j] = pm;
  }
  __syncthreads();
  {
    int o = t;
    float v = sGRed[o];
#pragma unroll
    for (int g = 1; g < 8; ++g) v = fmaxf(v, sGRed[g * 256 + o]);
    v += b2[o];
    // transposed store into final (B, C2, M) layout (pre-BN)
    outp[((size_t)(b * C2_ + o)) * M_ + m] = v;
  }
}

// ---------------------------------------------------------------------------
// 3) BN stats per channel (deterministic, double accum). One block / channel.
// ---------------------------------------------------------------------------
__global__ __launch_bounds__(256) void bn_stats_kernel(const float* __restrict__ outp,
                                                       const float* __restrict__ gamma,
                                                       float* __restrict__ stats) {
  const int o = blockIdx.x;
  const int t = threadIdx.x;
  double s = 0.0, s2 = 0.0;
  for (int b = 0; b < B_; ++b) {
    const float* p = outp + ((size_t)(b * C2_ + o)) * M_;
    for (int i = t; i < M_; i += 256) {
      float v = p[i];
      s += (double)v;
      s2 += (double)v * (double)v;
    }
  }
#pragma unroll
  for (int off = 32; off > 0; off >>= 1) {
    s += __shfl_xor(s, off);
    s2 += __shfl_xor(s2, off);
  }
  __shared__ double aS[4], aS2[4];
  if ((t & 63) == 0) { aS[t >> 6] = s; aS2[t >> 6] = s2; }
  __syncthreads();
  if (t == 0) {
    double S = aS[0] + aS[1] + aS[2] + aS[3];
    double S2 = aS2[0] + aS2[1] + aS2[2] + aS2[3];
    double mean = S / (double)(B_ * M_);
    double var = S2 / (double)(B_ * M_) - mean * mean;
    float rstd = 1.0f / sqrtf((float)var + 1e-5f);
    stats[o] = (float)mean;
    stats[C2_ + o] = gamma[o] * rstd;
  }
}

// ---------------------------------------------------------------------------
// 4) BN apply, in place on the (B,C2,M) output region. float4-vectorized.
// ---------------------------------------------------------------------------
__global__ __launch_bounds__(256) void bn_apply_kernel(float* __restrict__ outp,
                                                       const float* __restrict__ stats,
                                                       const float* __restrict__ beta) {
  const int i4 = blockIdx.x * 256 + threadIdx.x;  // B_*C2_*M_/4 = 262144
  const int ch = (i4 >> 9) & 255;                 // M_/4 = 512 float4 / chan
  const float mean = stats[ch];
  const float scale = stats[C2_ + ch];
  const float bt = beta[ch];
  float4 v = ((const float4*)outp)[i4];
  v.x = (v.x - mean) * scale + bt;
  v.y = (v.y - mean) * scale + bt;
  v.z = (v.z - mean) * scale + bt;
  v.w = (v.w - mean) * scale + bt;
  ((float4*)outp)[i4] = v;
}

// ---------------------------------------------------------------------------
extern "C" void kernel_launch(void* const* d_in, const int* in_sizes, int n_in,
                              void* d_out, int out_size, void* d_ws, size_t ws_size,
                              hipStream_t stream) {
  const float* xyz   = (const float*)d_in[0];
  const float* x     = (const float*)d_in[1];
  const float* W1    = (const float*)d_in[2];
  const float* b1    = (const float*)d_in[3];
  const float* W2    = (const float*)d_in[4];
  const float* b2    = (const float*)d_in[5];
  const float* gamma = (const float*)d_in[6];
  const float* beta  = (const float*)d_in[7];

  float* new_xyz = (float*)d_out;                       // (B, M, 3)
  float* outp    = (float*)d_out + (size_t)B_ * M_ * 3; // (B, C2, M)
  float* stats   = (float*)d_ws;                        // 2*C2 floats = 2 KB

  fps_kernel<<<B_, 512, 0, stream>>>(xyz, new_xyz);
  mlp_kernel<<<B_ * M_, 256, 0, stream>>>(xyz, x, W1, b1, W2, b2, new_xyz, outp);
  bn_stats_kernel<<<C2_, 256, 0, stream>>>(outp, gamma, stats);
  bn_apply_kernel<<<(B_ * C2_ * M_ / 4) / 256, 256, 0, stream>>>(outp, stats, beta);
}